// Round 6
// baseline (506.487 us; speedup 1.0000x reference)
//
#include <hip/hip_runtime.h>
#include <stdint.h>

// CausalMultiHeadAttention — round 6.
// fp32 in memory; 16-bit MFMA compute.
//  - cvt pass: x + all W -> bf16 once (RNE); GEMM loop reads bf16 (half the
//    bytes, no in-loop packing). Falls back to fp32+pk8 staging if ws_size
//    is too small for the extra 25 MB (branch on ws_size is capture-safe).
//  - GEMM: 128x128 tile, BK=64 (half the barriers), XOR-swizzled unpadded
//    LDS (balanced banks for both b128 writes and reads).
//  - Attention: 32 q/wave (2 subtiles share K-frags), 128 q/block,
//    double-buffered LDS K/V tiles: next tile's global loads issue before
//    compute, so the end-of-tile barrier no longer drains cold loads.
// ws (big path): x_bf | Wq..Wo_bf | Qw | Kw | Vtw ; O reuses x_bf (dead).

#define D_MODEL 1024
#define NHEAD   16
#define DK      64
#define BATCH   4
#define SEQ     2048
#define MTOT    (BATCH*SEQ)   // 8192

typedef unsigned short u16;
typedef unsigned int   u32;
typedef __bf16    bf16x8  __attribute__((ext_vector_type(8)));
typedef float     floatx4 __attribute__((ext_vector_type(4)));
typedef __fp16    fp16x2  __attribute__((ext_vector_type(2)));   // cvt_pkrtz native
typedef _Float16  half4_t __attribute__((ext_vector_type(4)));
typedef _Float16  half8_t __attribute__((ext_vector_type(8)));

__device__ __forceinline__ int imin(int a, int b){ return a < b ? a : b; }

// round-to-nearest-even f32 -> bf16
__device__ __forceinline__ u16 f2bf(float f){
  union { float f; u32 u; } c; c.f = f;
  u32 x = c.u;
  x += 0x7fffu + ((x >> 16) & 1u);
  return (u16)(x >> 16);
}
__device__ __forceinline__ u32 pkbf(float a, float b){   // RNE pack pair
  return ((u32)f2bf(b) << 16) | f2bf(a);
}
// f32 pair -> packed fp16 bits (RTZ, hardware packed cvt)
__device__ __forceinline__ u32 pkh(float a, float b){
  union { fp16x2 h; u32 u; } c; c.h = __builtin_amdgcn_cvt_pkrtz(a, b); return c.u;
}
// 8 fp32 -> 8 bf16 by truncation (one v_perm per pair) — fallback staging
__device__ __forceinline__ uint4 pk8(const float* __restrict__ p){
  uint4 a = *(const uint4*)p;
  uint4 b = *(const uint4*)(p + 4);
  uint4 r;
  r.x = __builtin_amdgcn_perm(a.y, a.x, 0x07060302);
  r.y = __builtin_amdgcn_perm(a.w, a.z, 0x07060302);
  r.z = __builtin_amdgcn_perm(b.y, b.x, 0x07060302);
  r.w = __builtin_amdgcn_perm(b.w, b.z, 0x07060302);
  return r;
}

// ---------------------------------------------------------------------------
// fp32 -> bf16 conversion pass (x and 4 weight matrices), RNE.
// 2048 elems/block: x = 4096 blocks, each W = 512 blocks.
// ---------------------------------------------------------------------------
__global__ __launch_bounds__(256, 8)
void cvt_bf16(const float* __restrict__ x,
              const float* __restrict__ w0, const float* __restrict__ w1,
              const float* __restrict__ w2, const float* __restrict__ w3,
              u16* __restrict__ xb, u16* __restrict__ wb0, u16* __restrict__ wb1,
              u16* __restrict__ wb2, u16* __restrict__ wb3)
{
  const int bx = blockIdx.x;
  const float* src; u16* dst; size_t off;
  if (bx < 4096) { src = x; dst = xb; off = (size_t)bx * 2048; }
  else {
    int i = bx - 4096; const int wi = i >> 9; i &= 511;
    src = wi == 0 ? w0 : wi == 1 ? w1 : wi == 2 ? w2 : w3;
    dst = wi == 0 ? wb0 : wi == 1 ? wb1 : wi == 2 ? wb2 : wb3;
    off = (size_t)i * 2048;
  }
  const int t = threadIdx.x;
  const float* p = src + off + t * 8;
  float4 a = *(const float4*)p;
  float4 b = *(const float4*)(p + 4);
  uint4 r;
  r.x = pkbf(a.x, a.y); r.y = pkbf(a.z, a.w);
  r.z = pkbf(b.x, b.y); r.w = pkbf(b.z, b.w);
  *(uint4*)(dst + off + t * 8) = r;
}

// ---------------------------------------------------------------------------
// GEMM: C[m,n] = (sum_k A[m,k]*W[n,k] + bias[n]) * scale.
// 128x128 tile, BK=64, 4 waves in 2x2, each wave 64x64 = 4x4 MFMA x2 ksub.
// LDS [128 rows][64 cols] u16, XOR-swizzled chunks: data chunk c of row r is
// stored at slot c^(r&7) -> both b128 staging writes and frag reads hit all
// 8 bank-groups uniformly (balanced, conflict-free).
// AB/WB: operand is bf16 (copy-stage) vs fp32 (pk8 trunc-stage).
// MODE 0: fp32 [m][N] (d_out) | MODE 1: fp16 [bh][s][dk] | MODE 2: fp16
// [bh][dk][s] (V^T). Operand order per mode so C-regs run on the fast axis.
// ---------------------------------------------------------------------------
template<int MODE, int AB, int WB>
__global__ __launch_bounds__(256, 3)
void gemm_bt(const void* __restrict__ Av, const void* __restrict__ Wv,
             const float* __restrict__ bias, void* __restrict__ outv,
             float scale)
{
  __shared__ __align__(16) u16 As[128*64];
  __shared__ __align__(16) u16 Bs[128*64];

  const int t    = threadIdx.x;
  const int n0   = blockIdx.x * 128;
  const int m0   = blockIdx.y * 128;
  const int wid  = t >> 6, lane = t & 63;
  const int wr   = wid >> 1, wc = wid & 1;
  const int quad = lane >> 4, l15 = lane & 15;
  const int sw   = l15 & 7;

  const float* Af32 = (const float*)Av; const u16* Ab16 = (const u16*)Av;
  const float* Wf32 = (const float*)Wv; const u16* Wb16 = (const u16*)Wv;

  // staging: 4 chunks (16B) per matrix per thread; slot = cpos, data = cpos^(r&7)
  int srow[4], scol[4], sslot[4];
#pragma unroll
  for (int it = 0; it < 4; ++it) {
    const int c = t + it * 256;
    srow[it]  = c >> 3;
    const int cpos = c & 7;
    scol[it]  = (cpos ^ (srow[it] & 7)) * 8;
    sslot[it] = srow[it] * 64 + cpos * 8;
  }

  floatx4 acc[4][4] = {};

  for (int k0 = 0; k0 < D_MODEL; k0 += 64) {
    __syncthreads();
#pragma unroll
    for (int it = 0; it < 4; ++it) {
      if (AB) *(uint4*)&As[sslot[it]] = *(const uint4*)(Ab16 + (size_t)(m0 + srow[it])*D_MODEL + k0 + scol[it]);
      else    *(uint4*)&As[sslot[it]] = pk8(Af32 + (size_t)(m0 + srow[it])*D_MODEL + k0 + scol[it]);
      if (WB) *(uint4*)&Bs[sslot[it]] = *(const uint4*)(Wb16 + (size_t)(n0 + srow[it])*D_MODEL + k0 + scol[it]);
      else    *(uint4*)&Bs[sslot[it]] = pk8(Wf32 + (size_t)(n0 + srow[it])*D_MODEL + k0 + scol[it]);
    }
    __syncthreads();
#pragma unroll
    for (int ks = 0; ks < 2; ++ks) {
      const int ac = ((ks * 4 + quad) ^ sw) * 8;
      bf16x8 af[4], bf[4];
#pragma unroll
      for (int i = 0; i < 4; ++i) {
        af[i] = *(const bf16x8*)&As[(wr*64 + i*16 + l15) * 64 + ac];
        bf[i] = *(const bf16x8*)&Bs[(wc*64 + i*16 + l15) * 64 + ac];
      }
#pragma unroll
      for (int mi = 0; mi < 4; ++mi)
#pragma unroll
        for (int nj = 0; nj < 4; ++nj) {
          if (MODE == 2)
            acc[mi][nj] = __builtin_amdgcn_mfma_f32_16x16x32_bf16(af[mi], bf[nj], acc[mi][nj], 0, 0, 0);
          else
            acc[mi][nj] = __builtin_amdgcn_mfma_f32_16x16x32_bf16(bf[nj], af[mi], acc[mi][nj], 0, 0, 0);
        }
    }
  }

  if (MODE != 2) {
    // lane = m, regs = n-consecutive
#pragma unroll
    for (int nj = 0; nj < 4; ++nj) {
      const int nb = n0 + wc*64 + nj*16 + quad*4;
      const float4 b4 = *(const float4*)(bias + nb);
#pragma unroll
      for (int mi = 0; mi < 4; ++mi) {
        const int m = m0 + wr*64 + mi*16 + l15;
        floatx4 d = acc[mi][nj];
        const float v0 = (d[0]+b4.x)*scale, v1 = (d[1]+b4.y)*scale;
        const float v2 = (d[2]+b4.z)*scale, v3 = (d[3]+b4.w)*scale;
        if (MODE == 0) {
          *(float4*)((float*)outv + (size_t)m*D_MODEL + nb) = make_float4(v0, v1, v2, v3);
        } else {
          const int b = m >> 11, s = m & 2047, h = nb >> 6, dd = nb & 63;
          u16* dst = (u16*)outv + ((((size_t)b*NHEAD + h)*SEQ + s) << 6) + dd;
          *(uint2*)dst = make_uint2(pkh(v0, v1), pkh(v2, v3));
        }
      }
    }
  } else {
    // lane = n (dd), regs = m (s)-consecutive
#pragma unroll
    for (int nj = 0; nj < 4; ++nj) {
      const int n  = n0 + wc*64 + nj*16 + l15;
      const float bvv = bias[n];
      const int h = n >> 6, dd = n & 63;
#pragma unroll
      for (int mi = 0; mi < 4; ++mi) {
        const int mb = m0 + wr*64 + mi*16 + quad*4;
        const int b = mb >> 11, s = mb & 2047;
        floatx4 d = acc[mi][nj];
        u16* dst = (u16*)outv + (((size_t)b*NHEAD + h)*DK + dd)*SEQ + s;
        *(uint2*)dst = make_uint2(pkh(d[0]+bvv, d[1]+bvv), pkh(d[2]+bvv, d[3]+bvv));
      }
    }
  }
}

// ---------------------------------------------------------------------------
// MFMA flash attention, double-buffered. Grid (SEQ/128 reversed, B*H),
// 256 thr = 4 waves x 32 queries (2 subtiles of 16 sharing K-fragments).
// Per 64-key tile: phase1 S^T = K·Q^T (16x16x32 f16, A-frag shared by both
// subtiles), online softmax in log2 domain (Q pre-scaled 0.125*log2e),
// phase2 O^T = V^T·P^T (16x16x16 f16, V-frag shared). Next tile's global
// loads issue before compute; LDS writes + one barrier at tile end.
// ---------------------------------------------------------------------------
__global__ __launch_bounds__(256, 3)
void attn_fwd(const _Float16* __restrict__ Q, const _Float16* __restrict__ K,
              const _Float16* __restrict__ Vt, u16* __restrict__ O)
{
  __shared__ __align__(16) _Float16 Ks[2][64][72];
  __shared__ __align__(16) _Float16 Vs[2][64][72];

  const int bh   = blockIdx.y;
  const int r0   = ((int)gridDim.x - 1 - (int)blockIdx.x) * 128;  // heavy first
  const int t    = threadIdx.x;
  const int w    = t >> 6, lane = t & 63;
  const int quad = lane >> 4, l15 = lane & 15;
  const int qb   = r0 + w * 32;

  half8_t qf[2][2];
  {
    const _Float16* Qp = Q + ((size_t)bh * SEQ + qb + l15) * DK + quad * 8;
#pragma unroll
    for (int qs = 0; qs < 2; ++qs)
#pragma unroll
      for (int ks = 0; ks < 2; ++ks)
        qf[qs][ks] = *(const half8_t*)(Qp + qs * 16 * DK + ks * 32);
  }

  float mrow[2] = { -1e30f, -1e30f };
  float lpart[2] = { 0.f, 0.f };
  floatx4 o[2][4] = {};

  const int sr = t >> 3, sc8 = (t & 7) * 8;
  const _Float16* Kb = K  + (size_t)bh * SEQ * DK;
  const _Float16* Vb = Vt + (size_t)bh * DK * SEQ;

  const int ntiles = (r0 >> 6) + 2;

  // prologue: stage tile 0 into buffer 0
  uint4 ka0 = *(const uint4*)(Kb + (size_t)(sr     ) * DK + sc8);
  uint4 ka1 = *(const uint4*)(Kb + (size_t)(sr + 32) * DK + sc8);
  uint4 va0 = *(const uint4*)(Vb + (size_t)(sr     ) * SEQ + sc8);
  uint4 va1 = *(const uint4*)(Vb + (size_t)(sr + 32) * SEQ + sc8);
  *(uint4*)&Ks[0][sr     ][sc8] = ka0;
  *(uint4*)&Ks[0][sr + 32][sc8] = ka1;
  *(uint4*)&Vs[0][sr     ][sc8] = va0;
  *(uint4*)&Vs[0][sr + 32][sc8] = va1;
  __syncthreads();

  for (int ti = 0; ti < ntiles; ++ti) {
    const int j0  = ti * 64;
    const int buf = ti & 1;
    const bool more = (ti + 1 < ntiles);
    if (more) {                                  // issue next tile's loads now
      const int jn = j0 + 64;
      ka0 = *(const uint4*)(Kb + (size_t)(jn + sr     ) * DK + sc8);
      ka1 = *(const uint4*)(Kb + (size_t)(jn + sr + 32) * DK + sc8);
      va0 = *(const uint4*)(Vb + (size_t)(sr     ) * SEQ + jn + sc8);
      va1 = *(const uint4*)(Vb + (size_t)(sr + 32) * SEQ + jn + sc8);
    }

    if (j0 <= qb + 31) {
      const int kt1 = imin(4, ((qb + 31 - j0) >> 4) + 1);
      const int kt0 = (j0 <= qb + 15) ? imin(4, ((qb + 15 - j0) >> 4) + 1) : 0;

      // ---- phase 1: S^T tiles, K-fragments shared by both subtiles
      floatx4 st[2][4];
#pragma unroll
      for (int kt = 0; kt < 4; ++kt) {
        if (kt < kt1) {
          half8_t a0 = *(const half8_t*)&Ks[buf][kt*16 + l15][quad*8];
          half8_t a1 = *(const half8_t*)&Ks[buf][kt*16 + l15][32 + quad*8];
          floatx4 s1 = {};
          s1 = __builtin_amdgcn_mfma_f32_16x16x32_f16(a0, qf[1][0], s1, 0, 0, 0);
          s1 = __builtin_amdgcn_mfma_f32_16x16x32_f16(a1, qf[1][1], s1, 0, 0, 0);
          st[1][kt] = s1;
          if (kt < kt0) {
            floatx4 s0 = {};
            s0 = __builtin_amdgcn_mfma_f32_16x16x32_f16(a0, qf[0][0], s0, 0, 0, 0);
            s0 = __builtin_amdgcn_mfma_f32_16x16x32_f16(a1, qf[0][1], s0, 0, 0, 0);
            st[0][kt] = s0;
          }
        }
      }

      // ---- mask + online softmax per subtile (log2 domain)
      half4_t pf[2][4];
#pragma unroll
      for (int qs = 0; qs < 2; ++qs) {
        const int ktm = qs ? kt1 : kt0;
        if (ktm > 0) {
          const int qlo = qb + qs * 16;
          const int query = qlo + l15;
#pragma unroll
          for (int kt = 0; kt < 4; ++kt) {
            if (kt < ktm && j0 + kt*16 + 15 > qlo) {
#pragma unroll
              for (int r = 0; r < 4; ++r)
                if (j0 + kt*16 + quad*4 + r > query) st[qs][kt][r] = -1e30f;
            }
          }
          float m0v = -1e30f;
#pragma unroll
          for (int kt = 0; kt < 4; ++kt)
            if (kt < ktm)
              m0v = fmaxf(m0v, fmaxf(fmaxf(st[qs][kt][0], st[qs][kt][1]),
                                     fmaxf(st[qs][kt][2], st[qs][kt][3])));
          m0v = fmaxf(m0v, __shfl_xor(m0v, 16));
          m0v = fmaxf(m0v, __shfl_xor(m0v, 32));
          const float mn    = fmaxf(mrow[qs], m0v);
          const float alpha = exp2f(mrow[qs] - mn);   // 0 on first live tile
          mrow[qs] = mn;
          lpart[qs] *= alpha;
#pragma unroll
          for (int kt = 0; kt < 4; ++kt) {
            if (kt < ktm) {
              const float p0 = exp2f(st[qs][kt][0] - mn), p1 = exp2f(st[qs][kt][1] - mn);
              const float p2 = exp2f(st[qs][kt][2] - mn), p3 = exp2f(st[qs][kt][3] - mn);
              lpart[qs] += (p0 + p1) + (p2 + p3);
              union { half4_t h; uint2 u; } pc;
              pc.u = make_uint2(pkh(p0, p1), pkh(p2, p3));
              pf[qs][kt] = pc.h;
            }
          }
#pragma unroll
          for (int dt = 0; dt < 4; ++dt) {
            o[qs][dt][0] *= alpha; o[qs][dt][1] *= alpha;
            o[qs][dt][2] *= alpha; o[qs][dt][3] *= alpha;
          }
        }
      }

      // ---- phase 2: O^T += V^T · P^T, V-fragments shared by both subtiles
#pragma unroll
      for (int dt = 0; dt < 4; ++dt)
#pragma unroll
        for (int kt = 0; kt < 4; ++kt) {
          if (kt < kt1) {
            half4_t vf = *(const half4_t*)&Vs[buf][dt*16 + l15][kt*16 + quad*4];
            o[1][dt] = __builtin_amdgcn_mfma_f32_16x16x16f16(vf, pf[1][kt], o[1][dt], 0, 0, 0);
            if (kt < kt0)
              o[0][dt] = __builtin_amdgcn_mfma_f32_16x16x16f16(vf, pf[0][kt], o[0][dt], 0, 0, 0);
          }
        }
    }

    if (more) {                                  // write next tile to other buf
      const int nb = buf ^ 1;
      *(uint4*)&Ks[nb][sr     ][sc8] = ka0;
      *(uint4*)&Ks[nb][sr + 32][sc8] = ka1;
      *(uint4*)&Vs[nb][sr     ][sc8] = va0;
      *(uint4*)&Vs[nb][sr + 32][sc8] = va1;
    }
    __syncthreads();
  }

  // ---- epilogue: deferred l reduction, O bf16 [B,S,D]
  const int b = bh >> 4, h = bh & 15;
#pragma unroll
  for (int qs = 0; qs < 2; ++qs) {
    float l = lpart[qs];
    l += __shfl_xor(l, 16);
    l += __shfl_xor(l, 32);
    const float inv = 1.0f / l;
    const int query = qb + qs*16 + l15;
    u16* Op = O + ((size_t)(b * SEQ + query)) * D_MODEL + h * DK + quad * 4;
#pragma unroll
    for (int dt = 0; dt < 4; ++dt) {
      u32 lo = ((u32)f2bf(o[qs][dt][1] * inv) << 16) | f2bf(o[qs][dt][0] * inv);
      u32 hi = ((u32)f2bf(o[qs][dt][3] * inv) << 16) | f2bf(o[qs][dt][2] * inv);
      *(uint2*)(Op + dt * 16) = make_uint2(lo, hi);
    }
  }
}

// ---------------------------------------------------------------------------
extern "C" void kernel_launch(void* const* d_in, const int* in_sizes, int n_in,
                              void* d_out, int out_size, void* d_ws, size_t ws_size,
                              hipStream_t stream)
{
  const float* x  = (const float*)d_in[0];
  const float* Wq = (const float*)d_in[1];
  const float* bq = (const float*)d_in[2];
  const float* Wk = (const float*)d_in[3];
  const float* bk = (const float*)d_in[4];
  const float* Wv = (const float*)d_in[5];
  const float* bv = (const float*)d_in[6];
  const float* Wo = (const float*)d_in[7];
  const float* bo = (const float*)d_in[8];

  const size_t tsz = (size_t)MTOT * D_MODEL;   // 8,388,608
  const size_t wsz = (size_t)D_MODEL * D_MODEL;

  const dim3 gg(D_MODEL/128, MTOT/128);        // 8 x 64 = 512 blocks
  const dim3 ga(SEQ/128, BATCH*NHEAD);         // 16 x 64 = 1024 blocks
  const float qscale = 0.18033688f;            // 1/sqrt(64) * log2(e)

  if (ws_size >= 2 * (tsz + 4*wsz + 3*tsz)) {  // 75.5 MB: bf16 fast path
    u16* xb  = (u16*)d_ws;
    u16* wqb = xb + tsz;
    u16* wkb = wqb + wsz;
    u16* wvb = wkb + wsz;
    u16* wob = wvb + wsz;
    u16* Qw  = wob + wsz;
    u16* Kw  = Qw + tsz;
    u16* Vtw = Kw + tsz;
    u16* Ow  = xb;                             // x_bf dead after QKV GEMMs

    cvt_bf16<<<4096 + 4*512, 256, 0, stream>>>(x, Wq, Wk, Wv, Wo,
                                               xb, wqb, wkb, wvb, wob);
    gemm_bt<1,1,1><<<gg, 256, 0, stream>>>(xb, wqb, bq, Qw,  qscale);
    gemm_bt<1,1,1><<<gg, 256, 0, stream>>>(xb, wkb, bk, Kw,  1.0f);
    gemm_bt<2,1,1><<<gg, 256, 0, stream>>>(xb, wvb, bv, Vtw, 1.0f);
    attn_fwd<<<ga, 256, 0, stream>>>(
        (const _Float16*)Qw, (const _Float16*)Kw, (const _Float16*)Vtw, Ow);
    gemm_bt<0,1,1><<<gg, 256, 0, stream>>>(Ow, wob, bo, d_out, 1.0f);
  } else {                                     // 67.1 MB fallback (round-5 ws)
    u16* Qw  = (u16*)d_ws;
    u16* Kw  = Qw + tsz;
    u16* Vtw = Kw + tsz;
    u16* Ow  = Vtw + tsz;

    gemm_bt<1,0,0><<<gg, 256, 0, stream>>>(x, Wq, bq, Qw,  qscale);
    gemm_bt<1,0,0><<<gg, 256, 0, stream>>>(x, Wk, bk, Kw,  1.0f);
    gemm_bt<2,0,0><<<gg, 256, 0, stream>>>(x, Wv, bv, Vtw, 1.0f);
    attn_fwd<<<ga, 256, 0, stream>>>(
        (const _Float16*)Qw, (const _Float16*)Kw, (const _Float16*)Vtw, Ow);
    gemm_bt<0,1,0><<<gg, 256, 0, stream>>>(Ow, Wo, bo, d_out, 1.0f);
  }
}